// Round 16
// baseline (2753.077 us; speedup 1.0000x reference)
//
#include <hip/hip_runtime.h>

// 2-layer biLSTM, B=128 T=256 IN=64 H=256, + fc to [128,1].
// R16 = R15 recurrence (verified, 2.566ms) + MFMA xg GEMM (hi/lo bf16 split).
// Recurrence: group = (dir, batch-block), 4 WGs x 256 thr; W_hh gates i,f in
// 128 pinned VGPRs, gates g,o in 136KB LDS; cross-WG h via tagged 8B pairs,
// RELAXED agent atomics at MALL (the one proven transport).
// xg GEMM: a*w ~= ah*wh + ah*wl + al*wh (error ~2^-18 rel). A/B fragments
// use the SAME k-mapping -> K-permutation invariance makes the within-
// fragment k layout assumption risk-free. C/D layout is the m89-verified
// col=lane&15, row=(lane>>4)*4+reg.

typedef unsigned long long ull;
typedef __attribute__((ext_vector_type(8))) short bf16x8;
typedef __attribute__((ext_vector_type(4))) float f32x4;

constexpr int B_ = 128, T_ = 256, IN_ = 64, H_ = 256;
constexpr int JW = 64;                    // hidden dims per WG (4-way j split)

#define KEEP_REG(x) asm volatile("" : "+v"(x))

__device__ __forceinline__ float sigmoid_(float x) { return 1.f / (1.f + __expf(-x)); }
__device__ __forceinline__ float tanh_(float x)    { return 1.f - 2.f / (1.f + __expf(2.f * x)); }
__device__ __forceinline__ int hidx(int k) { return (k >> 6) * 68 + (k & 63); }
__device__ __forceinline__ int widx(int gp, int jl, int ks, int kp) {
  return ((gp * 64 + jl) * 4 + ks) * 68 + kp;
}

// BB: batch rows per group. L0M: layer-0 mode (inline x via streamed W_ih).
template<int BB, bool L0M>
__global__ __launch_bounds__(256, 1)
void recur(const float* __restrict__ whh_f, const float* __restrict__ whh_b,
           const float* __restrict__ wih_f, const float* __restrict__ wih_b,
           const float* __restrict__ bih_f, const float* __restrict__ bhh_f,
           const float* __restrict__ bih_b, const float* __restrict__ bhh_b,
           const float* __restrict__ x,     // L0: [B][T][64]
           const float* __restrict__ xg,    // L1: [ns][B][1024], biases folded
           float* __restrict__ out0,        // L0: [T][B][512]
           float* __restrict__ hstate, float* __restrict__ cstate,  // [B][256]
           float* __restrict__ hfinal,      // [B][512] (L1)
           ull* __restrict__ ring,          // [gidx][2 slots][BB*256] pairs
           int ngroup, int dir_base, int nsteps, int step_base,
           int first, int save, int lastW)
{
  const int bid = blockIdx.x;
  const int kw  = bid & 3;
  const int gr  = (bid >> 2) % ngroup;
  const int dl  = (bid >> 2) / ngroup;
  const int d   = dir_base + dl;
  const int tid = threadIdx.x;
  const int jl  = tid >> 2;                 // 0..63
  const int ks  = tid & 3;                  // k-slice lane
  const int j   = kw * JW + jl;             // global hidden index
  const int bbase = gr * BB;
  const int gidx  = dl * ngroup + gr;

  const float* whh  = d ? whh_b : whh_f;
  const float* wihp = d ? wih_b : wih_f;

  // ---- VGPR gates i(0), f(1): 128 pinned floats ----
  float wr[2][64];
  #pragma unroll
  for (int g = 0; g < 2; ++g) {
    const float* wrow = whh + (long)(g * H_ + j) * H_ + ks * 64;
    #pragma unroll
    for (int q = 0; q < 16; ++q) {
      const float4 w4 = *(const float4*)(wrow + q * 4);
      wr[g][q*4+0] = w4.x; wr[g][q*4+1] = w4.y;
      wr[g][q*4+2] = w4.z; wr[g][q*4+3] = w4.w;
    }
  }
  #pragma unroll
  for (int g = 0; g < 2; ++g)
    #pragma unroll
    for (int q = 0; q < 64; ++q) KEEP_REG(wr[g][q]);

  // ---- LDS gates g(2), o(3): staged once ----
  __shared__ alignas(16) float wlds[2 * 64 * 4 * 68];   // 139264 B
  __shared__ alignas(16) float hbuf[2][BB][272];
  __shared__ alignas(16) float xt[2][4][64];            // L0 x tiles
  #pragma unroll
  for (int gp = 0; gp < 2; ++gp) {
    const float* wrow = whh + (long)((gp + 2) * H_ + j) * H_ + ks * 64;
    float* dst = &wlds[widx(gp, jl, ks, 0)];
    #pragma unroll
    for (int q = 0; q < 16; ++q)
      *(float4*)(dst + q * 4) = *(const float4*)(wrow + q * 4);
  }

  float br[4];
  if constexpr (L0M) {
    const float* bih = d ? bih_b : bih_f;
    const float* bhh = d ? bhh_b : bhh_f;
    #pragma unroll
    for (int g = 0; g < 4; ++g) br[g] = bih[g * H_ + j] + bhh[g * H_ + j];
  }

  // h(-1) / chunk restore
  for (int idx = tid; idx < BB * H_; idx += 256) {
    const int b = idx >> 8, k = idx & 255;
    hbuf[0][b][hidx(k)] = first ? 0.f : hstate[(long)(bbase + b) * H_ + k];
  }
  float cs[BB];
  #pragma unroll
  for (int b = 0; b < BB; ++b)
    cs[b] = first ? 0.f : cstate[(long)(bbase + b) * H_ + j];

  if constexpr (L0M) {
    if (tid < BB * 64) {
      const int b = tid >> 6, kx = tid & 63;
      const int t0 = d ? T_ - 1 : 0;
      xt[0][b][kx] = x[((long)(bbase + b) * T_ + t0) * IN_ + kx];
    }
  }
  float xr[BB][4], xn[BB][4];
  if constexpr (!L0M) {
    #pragma unroll
    for (int b = 0; b < BB; ++b)
      #pragma unroll
      for (int g = 0; g < 4; ++g)
        xr[b][g] = xg[(long)(bbase + b) * 1024 + g * H_ + j];
  }
  __syncthreads();

  const long ringstride = (long)2 * BB * H_;
  constexpr int NP = 3 * JW * BB;
  constexpr int NL = (NP + 255) / 256;

  for (int s = 0; s < nsteps; ++s) {
    const int p = s & 1, wp = p ^ 1;
    const int gstep = step_base + s;

    // A) L0: issue W_ih slice loads first (L2-fast; precede poll loads)
    float4 wa_[2][4], wb_[2][4];
    if constexpr (L0M) {
      #pragma unroll
      for (int gp = 0; gp < 2; ++gp) {
        const float* wa = wihp + (long)((2 * gp) * H_ + j) * IN_ + ks * 16;
        const float* wb = wihp + (long)((2 * gp + 1) * H_ + j) * IN_ + ks * 16;
        #pragma unroll
        for (int q = 0; q < 4; ++q) {
          wa_[gp][q] = *(const float4*)(wa + q * 4);
          wb_[gp][q] = *(const float4*)(wb + q * 4);
        }
      }
    }

    // A2) x / xg prefetch for next step
    float xpre = 0.f;
    if constexpr (L0M) {
      if (s + 1 < nsteps && tid < BB * 64) {
        const int b = tid >> 6, kx = tid & 63;
        const int ttn = d ? (T_ - 2 - s) : (s + 1);
        xpre = x[((long)(bbase + b) * T_ + ttn) * IN_ + kx];
      }
    } else {
      const int sn = (s + 1 < nsteps) ? s + 1 : s;
      #pragma unroll
      for (int b = 0; b < BB; ++b)
        #pragma unroll
        for (int g = 0; g < 4; ++g)
          xn[b][g] = xg[((long)sn * B_ + bbase + b) * 1024 + g * H_ + j];
    }

    // A3) issue poll loads early
    ull vv[NL];
    if (s > 0) {
      const long roff = gidx * ringstride + (long)((gstep - 1) & 1) * (BB * H_);
      #pragma unroll
      for (int q = 0; q < NL; ++q) {
        const int pidx = tid + q * 256;
        if (pidx < NP) {
          const int psl = pidx / (JW * BB), rem = pidx % (JW * BB);
          const int kwp = psl + (psl >= kw ? 1 : 0);
          vv[q] = __hip_atomic_load(ring + roff + (rem >> 6) * H_
                                        + kwp * JW + (rem & 63),
                                    __ATOMIC_RELAXED, __HIP_MEMORY_SCOPE_AGENT);
        }
      }
    }

    float acc[BB][4];
    #pragma unroll
    for (int b = 0; b < BB; ++b)
      #pragma unroll
      for (int g = 0; g < 4; ++g) acc[b][g] = 0.f;

    // B) L0: x-MAC with preloaded weights
    if constexpr (L0M) {
      #pragma unroll
      for (int gp = 0; gp < 2; ++gp) {
        const int g0 = 2 * gp, g1 = 2 * gp + 1;
        #pragma unroll
        for (int b = 0; b < BB; ++b) {
          #pragma unroll
          for (int q = 0; q < 4; ++q) {
            const float4 xv = *(const float4*)&xt[p][b][ks * 16 + q * 4];
            acc[b][g0] = fmaf(xv.x, wa_[gp][q].x, acc[b][g0]);
            acc[b][g0] = fmaf(xv.y, wa_[gp][q].y, acc[b][g0]);
            acc[b][g0] = fmaf(xv.z, wa_[gp][q].z, acc[b][g0]);
            acc[b][g0] = fmaf(xv.w, wa_[gp][q].w, acc[b][g0]);
            acc[b][g1] = fmaf(xv.x, wb_[gp][q].x, acc[b][g1]);
            acc[b][g1] = fmaf(xv.y, wb_[gp][q].y, acc[b][g1]);
            acc[b][g1] = fmaf(xv.z, wb_[gp][q].z, acc[b][g1]);
            acc[b][g1] = fmaf(xv.w, wb_[gp][q].w, acc[b][g1]);
          }
        }
      }
      if (s + 1 < nsteps && tid < BB * 64) {
        const int b = tid >> 6, kx = tid & 63;
        xt[wp][b][kx] = xpre;
      }
    }

    // C) spin-check polls; retry only stale entries
    if (s > 0) {
      const unsigned want = (unsigned)gstep;
      const long roff = gidx * ringstride + (long)((gstep - 1) & 1) * (BB * H_);
      long gd = 0;
      for (;;) {
        bool ok = true;
        #pragma unroll
        for (int q = 0; q < NL; ++q)
          if (tid + q * 256 < NP && (unsigned)(vv[q] >> 32) != want) ok = false;
        if (ok) break;
        if (++gd > (1L << 20)) break;   // bail instead of hanging
        __builtin_amdgcn_s_sleep(1);
        #pragma unroll
        for (int q = 0; q < NL; ++q) {
          const int pidx = tid + q * 256;
          if (pidx < NP && (unsigned)(vv[q] >> 32) != want) {
            const int psl = pidx / (JW * BB), rem = pidx % (JW * BB);
            const int kwp = psl + (psl >= kw ? 1 : 0);
            vv[q] = __hip_atomic_load(ring + roff + (rem >> 6) * H_
                                          + kwp * JW + (rem & 63),
                                      __ATOMIC_RELAXED, __HIP_MEMORY_SCOPE_AGENT);
          }
        }
      }
      #pragma unroll
      for (int q = 0; q < NL; ++q) {
        const int pidx = tid + q * 256;
        if (pidx < NP) {
          const int psl = pidx / (JW * BB), rem = pidx % (JW * BB);
          const int kwp = psl + (psl >= kw ? 1 : 0);
          hbuf[p][rem >> 6][hidx(kwp * JW + (rem & 63))] =
              __uint_as_float((unsigned)vv[q]);
        }
      }
    }
    __syncthreads();   // hbuf[p] complete; orders xt write vs next-iter read

    // D) hh MAC: reg gates i,f + LDS gates g,o
    #pragma unroll
    for (int q = 0; q < 16; ++q) {
      const float4 wg = *(const float4*)&wlds[widx(0, jl, ks, q * 4)];
      const float4 wo = *(const float4*)&wlds[widx(1, jl, ks, q * 4)];
      #pragma unroll
      for (int b = 0; b < BB; ++b) {
        const float4 hv = *(const float4*)&hbuf[p][b][ks * 68 + q * 4];
        acc[b][0] = fmaf(hv.x, wr[0][q*4+0], acc[b][0]);
        acc[b][0] = fmaf(hv.y, wr[0][q*4+1], acc[b][0]);
        acc[b][0] = fmaf(hv.z, wr[0][q*4+2], acc[b][0]);
        acc[b][0] = fmaf(hv.w, wr[0][q*4+3], acc[b][0]);
        acc[b][1] = fmaf(hv.x, wr[1][q*4+0], acc[b][1]);
        acc[b][1] = fmaf(hv.y, wr[1][q*4+1], acc[b][1]);
        acc[b][1] = fmaf(hv.z, wr[1][q*4+2], acc[b][1]);
        acc[b][1] = fmaf(hv.w, wr[1][q*4+3], acc[b][1]);
        acc[b][2] = fmaf(hv.x, wg.x, acc[b][2]);
        acc[b][2] = fmaf(hv.y, wg.y, acc[b][2]);
        acc[b][2] = fmaf(hv.z, wg.z, acc[b][2]);
        acc[b][2] = fmaf(hv.w, wg.w, acc[b][2]);
        acc[b][3] = fmaf(hv.x, wo.x, acc[b][3]);
        acc[b][3] = fmaf(hv.y, wo.y, acc[b][3]);
        acc[b][3] = fmaf(hv.z, wo.z, acc[b][3]);
        acc[b][3] = fmaf(hv.w, wo.w, acc[b][3]);
      }
    }

    // E) quad allreduce + activations
    float hv_[BB];
    #pragma unroll
    for (int b = 0; b < BB; ++b) {
      #pragma unroll
      for (int g = 0; g < 4; ++g) {
        float a = acc[b][g];
        a += __shfl_xor(a, 1, 64);
        a += __shfl_xor(a, 2, 64);
        if constexpr (L0M) acc[b][g] = a + br[g];
        else               acc[b][g] = a + xr[b][g];
      }
      const float ig = sigmoid_(acc[b][0]);
      const float fg = sigmoid_(acc[b][1]);
      const float gg = tanh_(acc[b][2]);
      const float og = sigmoid_(acc[b][3]);
      cs[b] = fg * cs[b] + ig * gg;
      hv_[b] = og * tanh_(cs[b]);
    }

    // F) publish + stores (lane ks handles batch row b=ks)
    if (ks < BB) {
      float hmine = hv_[0], cmine = cs[0];
      #pragma unroll
      for (int b = 1; b < BB; ++b)
        if (ks == b) { hmine = hv_[b]; cmine = cs[b]; }

      if (s < nsteps - 1) {
        const ull pv = ((ull)(unsigned)(gstep + 1) << 32)
                     | (unsigned)__float_as_uint(hmine);
        __hip_atomic_store(ring + gidx * ringstride
                               + (long)(gstep & 1) * (BB * H_) + ks * H_ + j,
                           pv, __ATOMIC_RELAXED, __HIP_MEMORY_SCOPE_AGENT);
      }
      hbuf[wp][ks][hidx(j)] = hmine;

      if constexpr (L0M) {
        const int tt = d ? (T_ - 1 - gstep) : gstep;
        out0[((long)tt * B_ + bbase + ks) * 512 + d * H_ + j] = hmine;
      } else {
        if (s == nsteps - 1 && lastW)
          hfinal[(long)(bbase + ks) * 512 + (d ? H_ : 0) + j] = hmine;
      }
      if (save && s == nsteps - 1) {
        hstate[(long)(bbase + ks) * H_ + j] = hmine;
        cstate[(long)(bbase + ks) * H_ + j] = cmine;
      }
    }

    if constexpr (!L0M) {
      #pragma unroll
      for (int b = 0; b < BB; ++b)
        #pragma unroll
        for (int g = 0; g < 4; ++g) xr[b][g] = xn[b][g];
    }
  }
}

// ---- fp32 GEMM (kept for the tiny L1-backward xg block only) ----
__global__ __launch_bounds__(256, 2)
void xg_gemm(const float* __restrict__ A, const float* __restrict__ W,
             const float* __restrict__ b1, const float* __restrict__ b2,
             float* __restrict__ C)
{
  __shared__ float As[16][128];
  __shared__ float Bs[16][132];
  const int tid = threadIdx.x;
  const int tx = tid & 15, ty = tid >> 4;
  const long m0 = (long)blockIdx.x * 128;
  const int  n0 = blockIdx.y * 128;
  const int sr = tid >> 1;
  const int sk = (tid & 1) * 8;
  const float* Ar = A + (m0 + sr) * 512 + sk;
  const float* Wr = W + (long)(n0 + sr) * 512 + sk;
  float acc[8][8];
  #pragma unroll
  for (int i = 0; i < 8; ++i)
    #pragma unroll
    for (int jj = 0; jj < 8; ++jj) acc[i][jj] = 0.f;

  for (int k0 = 0; k0 < 512; k0 += 16) {
    const float4 a0 = *(const float4*)(Ar + k0);
    const float4 a1 = *(const float4*)(Ar + k0 + 4);
    const float4 w0 = *(const float4*)(Wr + k0);
    const float4 w1 = *(const float4*)(Wr + k0 + 4);
    __syncthreads();
    As[sk+0][sr]=a0.x; As[sk+1][sr]=a0.y; As[sk+2][sr]=a0.z; As[sk+3][sr]=a0.w;
    As[sk+4][sr]=a1.x; As[sk+5][sr]=a1.y; As[sk+6][sr]=a1.z; As[sk+7][sr]=a1.w;
    Bs[sk+0][sr]=w0.x; Bs[sk+1][sr]=w0.y; Bs[sk+2][sr]=w0.z; Bs[sk+3][sr]=w0.w;
    Bs[sk+4][sr]=w1.x; Bs[sk+5][sr]=w1.y; Bs[sk+6][sr]=w1.z; Bs[sk+7][sr]=w1.w;
    __syncthreads();
    #pragma unroll
    for (int k = 0; k < 16; ++k) {
      const float4 av0 = *(const float4*)&As[k][ty * 8];
      const float4 av1 = *(const float4*)&As[k][ty * 8 + 4];
      const float4 bv0 = *(const float4*)&Bs[k][tx * 8];
      const float4 bv1 = *(const float4*)&Bs[k][tx * 8 + 4];
      const float a_[8] = {av0.x,av0.y,av0.z,av0.w,av1.x,av1.y,av1.z,av1.w};
      const float b_[8] = {bv0.x,bv0.y,bv0.z,bv0.w,bv1.x,bv1.y,bv1.z,bv1.w};
      #pragma unroll
      for (int i = 0; i < 8; ++i)
        #pragma unroll
        for (int jj = 0; jj < 8; ++jj)
          acc[i][jj] = fmaf(a_[i], b_[jj], acc[i][jj]);
    }
  }
  float bsum[8];
  #pragma unroll
  for (int jj = 0; jj < 8; ++jj) {
    const int col = n0 + tx * 8 + jj;
    bsum[jj] = b1[col] + b2[col];
  }
  #pragma unroll
  for (int i = 0; i < 8; ++i) {
    const long crow = m0 + ty * 8 + i;
    #pragma unroll
    for (int q = 0; q < 2; ++q) {
      float4 o;
      o.x = acc[i][q*4+0] + bsum[q*4+0];
      o.y = acc[i][q*4+1] + bsum[q*4+1];
      o.z = acc[i][q*4+2] + bsum[q*4+2];
      o.w = acc[i][q*4+3] + bsum[q*4+3];
      *(float4*)&C[crow * 1024 + n0 + tx * 8 + q * 4] = o;
    }
  }
}

// ---- hi/lo bf16 plane conversion: src f32 -> hp/lp packed (2 ushort/uint) --
__global__ __launch_bounds__(256)
void cvt_planes(const float* __restrict__ src,
                unsigned* __restrict__ hp, unsigned* __restrict__ lp, long n2)
{
  long i = (long)blockIdx.x * 256 + threadIdx.x;
  const long stride = (long)gridDim.x * 256;
  for (; i < n2; i += stride) {
    const float a0 = src[2 * i], a1 = src[2 * i + 1];
    const unsigned u0 = __float_as_uint(a0), u1 = __float_as_uint(a1);
    const unsigned h0 = (u0 + 0x7fffu + ((u0 >> 16) & 1u)) >> 16;
    const unsigned h1 = (u1 + 0x7fffu + ((u1 >> 16) & 1u)) >> 16;
    const float d0 = a0 - __uint_as_float(h0 << 16);
    const float d1 = a1 - __uint_as_float(h1 << 16);
    const unsigned ud0 = __float_as_uint(d0), ud1 = __float_as_uint(d1);
    const unsigned l0 = (ud0 + 0x7fffu + ((ud0 >> 16) & 1u)) >> 16;
    const unsigned l1 = (ud1 + 0x7fffu + ((ud1 >> 16) & 1u)) >> 16;
    hp[i] = h0 | (h1 << 16);
    lp[i] = l0 | (l1 << 16);
  }
}

// ---- MFMA GEMM: C[M][1024] = A[M][512]@W[1024][512]^T + b1 + b2 ----------
// Planes: Ah/Al, Wh/Wl as bf16 (ushort). Tile 64M x 128N, 4 waves (wave w =
// rows [w*16,w*16+16)). 3 mfma per 16x16 tile per k32: ah*wh + ah*wl + al*wh.
__global__ __launch_bounds__(256, 2)
void xg_mfma(const unsigned short* __restrict__ Ah, const unsigned short* __restrict__ Al,
             const unsigned short* __restrict__ Wh, const unsigned short* __restrict__ Wl,
             const float* __restrict__ b1, const float* __restrict__ b2,
             float* __restrict__ C)
{
  const int tid = threadIdx.x;
  const int w = tid >> 6, l = tid & 63;
  const int lr = l & 15, lg = l >> 4;          // in-tile row/col, k-group
  const long m0 = (long)blockIdx.x * 64 + w * 16;
  const int  n0 = blockIdx.y * 128;

  f32x4 acc[8];
  #pragma unroll
  for (int nt = 0; nt < 8; ++nt) acc[nt] = (f32x4){0.f, 0.f, 0.f, 0.f};

  const long abase = (m0 + lr) * 512 + lg * 8;
  for (int k0 = 0; k0 < 512; k0 += 32) {
    const bf16x8 a_h = *(const bf16x8*)(Ah + abase + k0);
    const bf16x8 a_l = *(const bf16x8*)(Al + abase + k0);
    #pragma unroll
    for (int nt = 0; nt < 8; ++nt) {
      const long wbase = (long)(n0 + nt * 16 + lr) * 512 + lg * 8 + k0;
      const bf16x8 b_h = *(const bf16x8*)(Wh + wbase);
      const bf16x8 b_l = *(const bf16x8*)(Wl + wbase);
      acc[nt] = __builtin_amdgcn_mfma_f32_16x16x32_bf16(a_h, b_h, acc[nt], 0, 0, 0);
      acc[nt] = __builtin_amdgcn_mfma_f32_16x16x32_bf16(a_h, b_l, acc[nt], 0, 0, 0);
      acc[nt] = __builtin_amdgcn_mfma_f32_16x16x32_bf16(a_l, b_h, acc[nt], 0, 0, 0);
    }
  }

  // Epilogue: D mapping col=lane&15, row=(lane>>4)*4+reg (m89-verified).
  #pragma unroll
  for (int nt = 0; nt < 8; ++nt) {
    const int col = n0 + nt * 16 + lr;
    const float bs = b1[col] + b2[col];
    #pragma unroll
    for (int r = 0; r < 4; ++r) {
      const long row = m0 + lg * 4 + r;
      C[row * 1024 + col] = acc[nt][r] + bs;
    }
  }
}

__global__ void fc_kernel(const float* __restrict__ hfinal,
                          const float* __restrict__ fc_w,
                          const float* __restrict__ fc_b,
                          float* __restrict__ out)
{
  const int tid = threadIdx.x;   // 512 threads: b = tid/4, quarter = tid%4
  const int b = tid >> 2, q = tid & 3;
  float s = 0.f;
  const float* hp = hfinal + b * 512 + q * 128;
  const float* wp = fc_w + q * 128;
  #pragma unroll 4
  for (int k = 0; k < 128; ++k) s += hp[k] * wp[k];
  s += __shfl_xor(s, 1, 64);
  s += __shfl_xor(s, 2, 64);
  if (q == 0) out[b] = s + fc_b[0];
}

extern "C" void kernel_launch(void* const* d_in, const int* in_sizes, int n_in,
                              void* d_out, int out_size, void* d_ws, size_t ws_size,
                              hipStream_t stream)
{
  const float* x     = (const float*)d_in[0];
  const float* wih0f = (const float*)d_in[1];
  const float* whh0f = (const float*)d_in[2];
  const float* bih0f = (const float*)d_in[3];
  const float* bhh0f = (const float*)d_in[4];
  const float* wih0b = (const float*)d_in[5];
  const float* whh0b = (const float*)d_in[6];
  const float* bih0b = (const float*)d_in[7];
  const float* bhh0b = (const float*)d_in[8];
  const float* wih1f = (const float*)d_in[9];
  const float* whh1f = (const float*)d_in[10];
  const float* bih1f = (const float*)d_in[11];
  const float* bhh1f = (const float*)d_in[12];
  const float* wih1b = (const float*)d_in[13];
  const float* whh1b = (const float*)d_in[14];
  const float* bih1b = (const float*)d_in[15];
  const float* bhh1b = (const float*)d_in[16];
  const float* fcw   = (const float*)d_in[17];
  const float* fcb   = (const float*)d_in[18];

  const size_t n_out0 = (size_t)T_ * B_ * 512;
  const size_t nring0 = 64ull * 2 * 4 * 256;   // ull: L0 (BB=4)
  const size_t nring1 = 64ull * 2 * 2 * 256;   // ull: L1 (BB=2)
  const size_t ringB  = (nring0 + nring1) * sizeof(ull);
  const size_t fixedf = n_out0 + (size_t)B_ * 1024 + 2 * (size_t)B_ * 256
                      + (size_t)B_ * 512;
  const size_t wplaneB = 2ull * 1024 * 512 * 2;           // Wh+Wl bytes

  // pick chunk size (includes bf16 planes)
  auto needB = [&](size_t ch) {
    const size_t aplaneB = 2ull * ch * B_ * 512 * 2;      // Ah+Al bytes
    return 4 * (fixedf + ch * B_ * 1024) + ringB + wplaneB + aplaneB + 256;
  };
  size_t CH = 0;
  const size_t cands[5] = {(size_t)T_, 64, 32, 16, 8};
  for (int i = 0; i < 5; ++i)
    if (needB(cands[i]) <= ws_size) { CH = cands[i]; break; }
  if (!CH) return;

  float* out0 = (float*)d_ws;
  float* xga  = out0 + n_out0;                      // [CH][B][1024]
  float* xg1b = xga + CH * B_ * 1024;               // [1][B][1024]
  float* hst1 = xg1b + (size_t)B_ * 1024;
  float* cst1 = hst1 + (size_t)B_ * 256;
  float* hfin = cst1 + (size_t)B_ * 256;            // [B][512]
  ull*  ring0 = (ull*)(hfin + (size_t)B_ * 512);
  ull*  ring1 = ring0 + nring0;
  unsigned short* Whp = (unsigned short*)(ring1 + nring1);
  unsigned short* Wlp = Whp + (size_t)1024 * 512;
  unsigned short* Ahp = Wlp + (size_t)1024 * 512;
  unsigned short* Alp = Ahp + CH * B_ * 512;

  hipMemsetAsync(ring0, 0, ringB, stream);

  // Layer 0: 2 dirs x 32 groups (BB=4) x 4 member WGs = 256 WGs, 1/CU.
  recur<4, true><<<dim3(256), dim3(256), 0, stream>>>(
      whh0f, whh0b, wih0f, wih0b, bih0f, bhh0f, bih0b, bhh0b,
      x, nullptr, out0, nullptr, nullptr, nullptr, ring0,
      /*ngroup*/32, /*dir_base*/0, /*nsteps*/T_, /*step_base*/0,
      /*first*/1, /*save*/0, /*lastW*/0);

  // Convert W_ih1f planes once (L1-forward weights).
  cvt_planes<<<dim3(256), dim3(256), 0, stream>>>(
      wih1f, (unsigned*)Whp, (unsigned*)Wlp, (long)1024 * 512 / 2);

  // Layer 1 backward: only t=T-1 needed -> one fp32 xg row-block + one step.
  xg_gemm<<<dim3(1, 8), dim3(256), 0, stream>>>(
      out0 + (size_t)(T_ - 1) * B_ * 512, wih1b, bih1b, bhh1b, xg1b);
  recur<2, false><<<dim3(256), dim3(256), 0, stream>>>(
      whh1f, whh1b, nullptr, nullptr, nullptr, nullptr, nullptr, nullptr,
      nullptr, xg1b, nullptr, hst1, cst1, hfin, ring1,
      /*ngroup*/64, /*dir_base*/1, /*nsteps*/1, /*step_base*/0,
      /*first*/1, /*save*/0, /*lastW*/1);

  // Layer 1 forward: per chunk, convert A planes -> MFMA xg -> recurrence.
  const int nch = (int)(T_ / CH);
  for (int c = 0; c < nch; ++c) {
    cvt_planes<<<dim3(2048), dim3(256), 0, stream>>>(
        out0 + (size_t)c * CH * B_ * 512,
        (unsigned*)Ahp, (unsigned*)Alp, (long)CH * B_ * 512 / 2);
    xg_mfma<<<dim3((unsigned)(CH * B_ / 64), 8), dim3(256), 0, stream>>>(
        Ahp, Alp, Whp, Wlp, bih1f, bhh1f, xga);
    recur<2, false><<<dim3(256), dim3(256), 0, stream>>>(
        whh1f, whh1b, nullptr, nullptr, nullptr, nullptr, nullptr, nullptr,
        nullptr, xga, nullptr, hst1, cst1, hfin, ring1,
        /*ngroup*/64, /*dir_base*/0, /*nsteps*/(int)CH, /*step_base*/(int)(c * CH),
        /*first*/c == 0 ? 1 : 0, /*save*/1, /*lastW*/c == nch - 1 ? 1 : 0);
  }

  fc_kernel<<<dim3(1), dim3(512), 0, stream>>>(hfin, fcw, fcb, (float*)d_out);
}

// Round 17
// 2318.840 us; speedup vs baseline: 1.1873x; 1.1873x over previous
//
#include <hip/hip_runtime.h>

// 2-layer biLSTM, B=128 T=256 IN=64 H=256, + fc to [128,1].
// R17 = R15 protocol (verified 2.566ms) with 512-thread recurrence WGs:
// 8-way k-split -> 2 waves/SIMD hides LDS/FMA latency in the hh-MAC while
// per-thread pinned weights stay at 64 VGPRs (under the 128-reg cap that
// 512-thread WGs get; R12's spill was at 192 pinned).
// Group = (dir, batch-block), 4 WGs j-split; thread = (jl 0..63, ks 0..7).
// W_hh gates i,f in 64 pinned VGPRs; gates g,o in 144KB LDS (bank-uniform
// layout). Cross-WG h: tagged 8B pairs, RELAXED agent atomics at MALL (the
// one proven transport). xg GEMM: fp32 LDS-tiled (R16's MFMA regressed).

typedef unsigned long long ull;

constexpr int B_ = 128, T_ = 256, IN_ = 64, H_ = 256;
constexpr int JW = 64;                    // hidden dims per WG (4-way j split)

#define KEEP_REG(x) asm volatile("" : "+v"(x))

__device__ __forceinline__ float sigmoid_(float x) { return 1.f / (1.f + __expf(-x)); }
__device__ __forceinline__ float tanh_(float x)    { return 1.f - 2.f / (1.f + __expf(2.f * x)); }
// hbuf row: 8 chunks of 32 padded to 36 (ks-stride = +4 banks -> full spread)
__device__ __forceinline__ int hidx(int k) { return (k >> 5) * 36 + (k & 31); }
// LDS weight layout: ((gp*64+jl)*8+ks)*36 + kp ; bank-start 4*(lane%8) ->
// uniform 8 touches/bank = ds_read_b128 floor.
__device__ __forceinline__ int widx(int gp, int jl, int ks, int kp) {
  return ((gp * 64 + jl) * 8 + ks) * 36 + kp;
}

// BB: batch rows per group. L0M: layer-0 mode (inline x via streamed W_ih).
template<int BB, bool L0M>
__global__ __launch_bounds__(512, 1)
void recur(const float* __restrict__ whh_f, const float* __restrict__ whh_b,
           const float* __restrict__ wih_f, const float* __restrict__ wih_b,
           const float* __restrict__ bih_f, const float* __restrict__ bhh_f,
           const float* __restrict__ bih_b, const float* __restrict__ bhh_b,
           const float* __restrict__ x,     // L0: [B][T][64]
           const float* __restrict__ xg,    // L1: [ns][B][1024], biases folded
           float* __restrict__ out0,        // L0: [T][B][512]
           float* __restrict__ hstate, float* __restrict__ cstate,  // [B][256]
           float* __restrict__ hfinal,      // [B][512] (L1)
           ull* __restrict__ ring,          // [gidx][2 slots][BB*256] pairs
           int ngroup, int dir_base, int nsteps, int step_base,
           int first, int save, int lastW)
{
  const int bid = blockIdx.x;
  const int kw  = bid & 3;
  const int gr  = (bid >> 2) % ngroup;
  const int dl  = (bid >> 2) / ngroup;
  const int d   = dir_base + dl;
  const int tid = threadIdx.x;              // 0..511
  const int jl  = tid >> 3;                 // 0..63
  const int ks  = tid & 7;                  // k-slice lane (32 k each)
  const int j   = kw * JW + jl;             // global hidden index
  const int bbase = gr * BB;
  const int gidx  = dl * ngroup + gr;

  const float* whh  = d ? whh_b : whh_f;
  const float* wihp = d ? wih_b : wih_f;

  // ---- VGPR gates i(0), f(1): 64 pinned floats ----
  float wr[2][32];
  #pragma unroll
  for (int g = 0; g < 2; ++g) {
    const float* wrow = whh + (long)(g * H_ + j) * H_ + ks * 32;
    #pragma unroll
    for (int q = 0; q < 8; ++q) {
      const float4 w4 = *(const float4*)(wrow + q * 4);
      wr[g][q*4+0] = w4.x; wr[g][q*4+1] = w4.y;
      wr[g][q*4+2] = w4.z; wr[g][q*4+3] = w4.w;
    }
  }
  #pragma unroll
  for (int g = 0; g < 2; ++g)
    #pragma unroll
    for (int q = 0; q < 32; ++q) KEEP_REG(wr[g][q]);

  // ---- LDS gates g(2), o(3): staged once ----
  __shared__ alignas(16) float wlds[2 * 64 * 8 * 36];   // 147456 B
  __shared__ alignas(16) float hbuf[2][BB][288];        // 8x36 padded chunks
  __shared__ alignas(16) float xt[2][4][64];            // L0 x tiles
  #pragma unroll
  for (int gp = 0; gp < 2; ++gp) {
    const float* wrow = whh + (long)((gp + 2) * H_ + j) * H_ + ks * 32;
    float* dst = &wlds[widx(gp, jl, ks, 0)];
    #pragma unroll
    for (int q = 0; q < 8; ++q)
      *(float4*)(dst + q * 4) = *(const float4*)(wrow + q * 4);
  }

  float br[4];
  if constexpr (L0M) {
    const float* bih = d ? bih_b : bih_f;
    const float* bhh = d ? bhh_b : bhh_f;
    #pragma unroll
    for (int g = 0; g < 4; ++g) br[g] = bih[g * H_ + j] + bhh[g * H_ + j];
  }

  // h(-1) / chunk restore
  for (int idx = tid; idx < BB * H_; idx += 512) {
    const int b = idx >> 8, k = idx & 255;
    hbuf[0][b][hidx(k)] = first ? 0.f : hstate[(long)(bbase + b) * H_ + k];
  }
  float cs[BB];
  #pragma unroll
  for (int b = 0; b < BB; ++b)
    cs[b] = first ? 0.f : cstate[(long)(bbase + b) * H_ + j];

  if constexpr (L0M) {
    if (tid < BB * 64) {
      const int b = tid >> 6, kx = tid & 63;
      const int t0 = d ? T_ - 1 : 0;
      xt[0][b][kx] = x[((long)(bbase + b) * T_ + t0) * IN_ + kx];
    }
  }
  float xr[BB][4], xn[BB][4];
  if constexpr (!L0M) {
    #pragma unroll
    for (int b = 0; b < BB; ++b)
      #pragma unroll
      for (int g = 0; g < 4; ++g)
        xr[b][g] = xg[(long)(bbase + b) * 1024 + g * H_ + j];
  }
  __syncthreads();

  const long ringstride = (long)2 * BB * H_;
  constexpr int NP = 3 * JW * BB;
  constexpr int NL = (NP + 511) / 512;

  for (int s = 0; s < nsteps; ++s) {
    const int p = s & 1, wp = p ^ 1;
    const int gstep = step_base + s;

    // A2) x / xg prefetch for next step (issued before polls, used late)
    float xpre = 0.f;
    if constexpr (L0M) {
      if (s + 1 < nsteps && tid < BB * 64) {
        const int b = tid >> 6, kx = tid & 63;
        const int ttn = d ? (T_ - 2 - s) : (s + 1);
        xpre = x[((long)(bbase + b) * T_ + ttn) * IN_ + kx];
      }
    } else {
      const int sn = (s + 1 < nsteps) ? s + 1 : s;
      #pragma unroll
      for (int b = 0; b < BB; ++b)
        #pragma unroll
        for (int g = 0; g < 4; ++g)
          xn[b][g] = xg[((long)sn * B_ + bbase + b) * 1024 + g * H_ + j];
    }

    // A3) issue poll loads early: their MALL RTT overlaps the x-MAC below.
    ull vv[NL];
    if (s > 0) {
      const long roff = gidx * ringstride + (long)((gstep - 1) & 1) * (BB * H_);
      #pragma unroll
      for (int q = 0; q < NL; ++q) {
        const int pidx = tid + q * 512;
        if (pidx < NP) {
          const int psl = pidx / (JW * BB), rem = pidx % (JW * BB);
          const int kwp = psl + (psl >= kw ? 1 : 0);
          vv[q] = __hip_atomic_load(ring + roff + (rem >> 6) * H_
                                        + kwp * JW + (rem & 63),
                                    __ATOMIC_RELAXED, __HIP_MEMORY_SCOPE_AGENT);
        }
      }
    }

    float acc[BB][4];
    #pragma unroll
    for (int b = 0; b < BB; ++b)
      #pragma unroll
      for (int g = 0; g < 4; ++g) acc[b][g] = 0.f;

    // B) L0: x-MAC (thread owns x cols [ks*8, ks*8+8); weights L2-streamed,
    //    per-gate to bound live registers)
    if constexpr (L0M) {
      #pragma unroll
      for (int g = 0; g < 4; ++g) {
        const float* wa = wihp + (long)(g * H_ + j) * IN_ + ks * 8;
        const float4 w0 = *(const float4*)(wa);
        const float4 w1 = *(const float4*)(wa + 4);
        #pragma unroll
        for (int b = 0; b < BB; ++b) {
          const float4 x0 = *(const float4*)&xt[p][b][ks * 8];
          const float4 x1 = *(const float4*)&xt[p][b][ks * 8 + 4];
          acc[b][g] = fmaf(x0.x, w0.x, acc[b][g]);
          acc[b][g] = fmaf(x0.y, w0.y, acc[b][g]);
          acc[b][g] = fmaf(x0.z, w0.z, acc[b][g]);
          acc[b][g] = fmaf(x0.w, w0.w, acc[b][g]);
          acc[b][g] = fmaf(x1.x, w1.x, acc[b][g]);
          acc[b][g] = fmaf(x1.y, w1.y, acc[b][g]);
          acc[b][g] = fmaf(x1.z, w1.z, acc[b][g]);
          acc[b][g] = fmaf(x1.w, w1.w, acc[b][g]);
        }
      }
      // write next step's x tile BEFORE the barrier (race-fix ordering)
      if (s + 1 < nsteps && tid < BB * 64) {
        const int b = tid >> 6, kx = tid & 63;
        xt[wp][b][kx] = xpre;
      }
    }

    // C) spin-check polls; retry only stale entries
    if (s > 0) {
      const unsigned want = (unsigned)gstep;
      const long roff = gidx * ringstride + (long)((gstep - 1) & 1) * (BB * H_);
      long gd = 0;
      for (;;) {
        bool ok = true;
        #pragma unroll
        for (int q = 0; q < NL; ++q)
          if (tid + q * 512 < NP && (unsigned)(vv[q] >> 32) != want) ok = false;
        if (ok) break;
        if (++gd > (1L << 20)) break;   // bail instead of hanging
        __builtin_amdgcn_s_sleep(1);
        #pragma unroll
        for (int q = 0; q < NL; ++q) {
          const int pidx = tid + q * 512;
          if (pidx < NP && (unsigned)(vv[q] >> 32) != want) {
            const int psl = pidx / (JW * BB), rem = pidx % (JW * BB);
            const int kwp = psl + (psl >= kw ? 1 : 0);
            vv[q] = __hip_atomic_load(ring + roff + (rem >> 6) * H_
                                          + kwp * JW + (rem & 63),
                                      __ATOMIC_RELAXED, __HIP_MEMORY_SCOPE_AGENT);
          }
        }
      }
      #pragma unroll
      for (int q = 0; q < NL; ++q) {
        const int pidx = tid + q * 512;
        if (pidx < NP) {
          const int psl = pidx / (JW * BB), rem = pidx % (JW * BB);
          const int kwp = psl + (psl >= kw ? 1 : 0);
          hbuf[p][rem >> 6][hidx(kwp * JW + (rem & 63))] =
              __uint_as_float((unsigned)vv[q]);
        }
      }
    }
    __syncthreads();   // hbuf[p] complete; orders xt write vs next-iter read

    // D) hh MAC over own 32-k slice: reg gates i,f + LDS gates g,o
    #pragma unroll
    for (int q = 0; q < 8; ++q) {
      const float4 wg = *(const float4*)&wlds[widx(0, jl, ks, q * 4)];
      const float4 wo = *(const float4*)&wlds[widx(1, jl, ks, q * 4)];
      #pragma unroll
      for (int b = 0; b < BB; ++b) {
        const float4 hv = *(const float4*)&hbuf[p][b][ks * 36 + q * 4];
        acc[b][0] = fmaf(hv.x, wr[0][q*4+0], acc[b][0]);
        acc[b][0] = fmaf(hv.y, wr[0][q*4+1], acc[b][0]);
        acc[b][0] = fmaf(hv.z, wr[0][q*4+2], acc[b][0]);
        acc[b][0] = fmaf(hv.w, wr[0][q*4+3], acc[b][0]);
        acc[b][1] = fmaf(hv.x, wr[1][q*4+0], acc[b][1]);
        acc[b][1] = fmaf(hv.y, wr[1][q*4+1], acc[b][1]);
        acc[b][1] = fmaf(hv.z, wr[1][q*4+2], acc[b][1]);
        acc[b][1] = fmaf(hv.w, wr[1][q*4+3], acc[b][1]);
        acc[b][2] = fmaf(hv.x, wg.x, acc[b][2]);
        acc[b][2] = fmaf(hv.y, wg.y, acc[b][2]);
        acc[b][2] = fmaf(hv.z, wg.z, acc[b][2]);
        acc[b][2] = fmaf(hv.w, wg.w, acc[b][2]);
        acc[b][3] = fmaf(hv.x, wo.x, acc[b][3]);
        acc[b][3] = fmaf(hv.y, wo.y, acc[b][3]);
        acc[b][3] = fmaf(hv.z, wo.z, acc[b][3]);
        acc[b][3] = fmaf(hv.w, wo.w, acc[b][3]);
      }
    }

    // E) 8-lane allreduce + activations (replicated across the octet)
    float hv_[BB];
    #pragma unroll
    for (int b = 0; b < BB; ++b) {
      #pragma unroll
      for (int g = 0; g < 4; ++g) {
        float a = acc[b][g];
        a += __shfl_xor(a, 1, 64);
        a += __shfl_xor(a, 2, 64);
        a += __shfl_xor(a, 4, 64);
        if constexpr (L0M) acc[b][g] = a + br[g];
        else               acc[b][g] = a + xr[b][g];
      }
      const float ig = sigmoid_(acc[b][0]);
      const float fg = sigmoid_(acc[b][1]);
      const float gg = tanh_(acc[b][2]);
      const float og = sigmoid_(acc[b][3]);
      cs[b] = fg * cs[b] + ig * gg;
      hv_[b] = og * tanh_(cs[b]);
    }

    // F) publish + stores (lane ks handles batch row b=ks)
    if (ks < BB) {
      float hmine = hv_[0], cmine = cs[0];
      #pragma unroll
      for (int b = 1; b < BB; ++b)
        if (ks == b) { hmine = hv_[b]; cmine = cs[b]; }

      if (s < nsteps - 1) {
        const ull pv = ((ull)(unsigned)(gstep + 1) << 32)
                     | (unsigned)__float_as_uint(hmine);
        __hip_atomic_store(ring + gidx * ringstride
                               + (long)(gstep & 1) * (BB * H_) + ks * H_ + j,
                           pv, __ATOMIC_RELAXED, __HIP_MEMORY_SCOPE_AGENT);
      }
      hbuf[wp][ks][hidx(j)] = hmine;

      if constexpr (L0M) {
        const int tt = d ? (T_ - 1 - gstep) : gstep;
        out0[((long)tt * B_ + bbase + ks) * 512 + d * H_ + j] = hmine;
      } else {
        if (s == nsteps - 1 && lastW)
          hfinal[(long)(bbase + ks) * 512 + (d ? H_ : 0) + j] = hmine;
      }
      if (save && s == nsteps - 1) {
        hstate[(long)(bbase + ks) * H_ + j] = hmine;
        cstate[(long)(bbase + ks) * H_ + j] = cmine;
      }
    }

    // deferred reg update of prefetched xg (registers: no hazard)
    if constexpr (!L0M) {
      #pragma unroll
      for (int b = 0; b < BB; ++b)
        #pragma unroll
        for (int g = 0; g < 4; ++g) xr[b][g] = xn[b][g];
    }
  }
}

// C[M][1024] = A[M][512] @ W[1024][512]^T + b1 + b2.  M = gridDim.x*128.
__global__ __launch_bounds__(256, 2)
void xg_gemm(const float* __restrict__ A, const float* __restrict__ W,
             const float* __restrict__ b1, const float* __restrict__ b2,
             float* __restrict__ C)
{
  __shared__ float As[16][128];
  __shared__ float Bs[16][132];
  const int tid = threadIdx.x;
  const int tx = tid & 15, ty = tid >> 4;
  const long m0 = (long)blockIdx.x * 128;
  const int  n0 = blockIdx.y * 128;
  const int sr = tid >> 1;
  const int sk = (tid & 1) * 8;
  const float* Ar = A + (m0 + sr) * 512 + sk;
  const float* Wr = W + (long)(n0 + sr) * 512 + sk;
  float acc[8][8];
  #pragma unroll
  for (int i = 0; i < 8; ++i)
    #pragma unroll
    for (int jj = 0; jj < 8; ++jj) acc[i][jj] = 0.f;

  for (int k0 = 0; k0 < 512; k0 += 16) {
    const float4 a0 = *(const float4*)(Ar + k0);
    const float4 a1 = *(const float4*)(Ar + k0 + 4);
    const float4 w0 = *(const float4*)(Wr + k0);
    const float4 w1 = *(const float4*)(Wr + k0 + 4);
    __syncthreads();
    As[sk+0][sr]=a0.x; As[sk+1][sr]=a0.y; As[sk+2][sr]=a0.z; As[sk+3][sr]=a0.w;
    As[sk+4][sr]=a1.x; As[sk+5][sr]=a1.y; As[sk+6][sr]=a1.z; As[sk+7][sr]=a1.w;
    Bs[sk+0][sr]=w0.x; Bs[sk+1][sr]=w0.y; Bs[sk+2][sr]=w0.z; Bs[sk+3][sr]=w0.w;
    Bs[sk+4][sr]=w1.x; Bs[sk+5][sr]=w1.y; Bs[sk+6][sr]=w1.z; Bs[sk+7][sr]=w1.w;
    __syncthreads();
    #pragma unroll
    for (int k = 0; k < 16; ++k) {
      const float4 av0 = *(const float4*)&As[k][ty * 8];
      const float4 av1 = *(const float4*)&As[k][ty * 8 + 4];
      const float4 bv0 = *(const float4*)&Bs[k][tx * 8];
      const float4 bv1 = *(const float4*)&Bs[k][tx * 8 + 4];
      const float a_[8] = {av0.x,av0.y,av0.z,av0.w,av1.x,av1.y,av1.z,av1.w};
      const float b_[8] = {bv0.x,bv0.y,bv0.z,bv0.w,bv1.x,bv1.y,bv1.z,bv1.w};
      #pragma unroll
      for (int i = 0; i < 8; ++i)
        #pragma unroll
        for (int jj = 0; jj < 8; ++jj)
          acc[i][jj] = fmaf(a_[i], b_[jj], acc[i][jj]);
    }
  }
  float bsum[8];
  #pragma unroll
  for (int jj = 0; jj < 8; ++jj) {
    const int col = n0 + tx * 8 + jj;
    bsum[jj] = b1[col] + b2[col];
  }
  #pragma unroll
  for (int i = 0; i < 8; ++i) {
    const long crow = m0 + ty * 8 + i;
    #pragma unroll
    for (int q = 0; q < 2; ++q) {
      float4 o;
      o.x = acc[i][q*4+0] + bsum[q*4+0];
      o.y = acc[i][q*4+1] + bsum[q*4+1];
      o.z = acc[i][q*4+2] + bsum[q*4+2];
      o.w = acc[i][q*4+3] + bsum[q*4+3];
      *(float4*)&C[crow * 1024 + n0 + tx * 8 + q * 4] = o;
    }
  }
}

__global__ void fc_kernel(const float* __restrict__ hfinal,
                          const float* __restrict__ fc_w,
                          const float* __restrict__ fc_b,
                          float* __restrict__ out)
{
  const int tid = threadIdx.x;   // 512 threads: b = tid/4, quarter = tid%4
  const int b = tid >> 2, q = tid & 3;
  float s = 0.f;
  const float* hp = hfinal + b * 512 + q * 128;
  const float* wp = fc_w + q * 128;
  #pragma unroll 4
  for (int k = 0; k < 128; ++k) s += hp[k] * wp[k];
  s += __shfl_xor(s, 1, 64);
  s += __shfl_xor(s, 2, 64);
  if (q == 0) out[b] = s + fc_b[0];
}

extern "C" void kernel_launch(void* const* d_in, const int* in_sizes, int n_in,
                              void* d_out, int out_size, void* d_ws, size_t ws_size,
                              hipStream_t stream)
{
  const float* x     = (const float*)d_in[0];
  const float* wih0f = (const float*)d_in[1];
  const float* whh0f = (const float*)d_in[2];
  const float* bih0f = (const float*)d_in[3];
  const float* bhh0f = (const float*)d_in[4];
  const float* wih0b = (const float*)d_in[5];
  const float* whh0b = (const float*)d_in[6];
  const float* bih0b = (const float*)d_in[7];
  const float* bhh0b = (const float*)d_in[8];
  const float* wih1f = (const float*)d_in[9];
  const float* whh1f = (const float*)d_in[10];
  const float* bih1f = (const float*)d_in[11];
  const float* bhh1f = (const float*)d_in[12];
  const float* wih1b = (const float*)d_in[13];
  const float* whh1b = (const float*)d_in[14];
  const float* bih1b = (const float*)d_in[15];
  const float* bhh1b = (const float*)d_in[16];
  const float* fcw   = (const float*)d_in[17];
  const float* fcb   = (const float*)d_in[18];

  const size_t n_out0 = (size_t)T_ * B_ * 512;
  const size_t nring0 = 64ull * 2 * 4 * 256;   // ull: L0 (BB=4)
  const size_t nring1 = 64ull * 2 * 2 * 256;   // ull: L1 (BB=2)
  const size_t ringB  = (nring0 + nring1) * sizeof(ull);
  const size_t fixedf = n_out0 + (size_t)B_ * 1024 + 2 * (size_t)B_ * 256
                      + (size_t)B_ * 512;

  // xg area: full T-precompute if it fits, else chunked.
  int CH = 0; bool full = false;
  if (4 * (fixedf + (size_t)T_ * B_ * 1024) + ringB <= ws_size) {
    full = true; CH = T_;
  } else {
    const int cands[4] = {64, 32, 16, 8};
    for (int i = 0; i < 4; ++i)
      if (4 * (fixedf + (size_t)cands[i] * B_ * 1024) + ringB <= ws_size) {
        CH = cands[i]; break;
      }
  }
  if (!CH) return;

  float* out0 = (float*)d_ws;
  float* xga  = out0 + n_out0;                      // [CH][B][1024]
  float* xg1b = xga + (size_t)CH * B_ * 1024;       // [1][B][1024]
  float* hst1 = xg1b + (size_t)B_ * 1024;
  float* cst1 = hst1 + (size_t)B_ * 256;
  float* hfin = cst1 + (size_t)B_ * 256;            // [B][512]
  ull*  ring0 = (ull*)(hfin + (size_t)B_ * 512);
  ull*  ring1 = ring0 + nring0;

  hipMemsetAsync(ring0, 0, ringB, stream);

  // Layer 0: 2 dirs x 32 groups (BB=4) x 4 member WGs = 256 WGs, 1/CU.
  recur<4, true><<<dim3(256), dim3(512), 0, stream>>>(
      whh0f, whh0b, wih0f, wih0b, bih0f, bhh0f, bih0b, bhh0b,
      x, nullptr, out0, nullptr, nullptr, nullptr, ring0,
      /*ngroup*/32, /*dir_base*/0, /*nsteps*/T_, /*step_base*/0,
      /*first*/1, /*save*/0, /*lastW*/0);

  // Layer 1 backward: only t=T-1 needed -> one xg row-block + one step.
  xg_gemm<<<dim3(1, 8), dim3(256), 0, stream>>>(
      out0 + (size_t)(T_ - 1) * B_ * 512, wih1b, bih1b, bhh1b, xg1b);
  recur<2, false><<<dim3(256), dim3(512), 0, stream>>>(
      whh1f, whh1b, nullptr, nullptr, nullptr, nullptr, nullptr, nullptr,
      nullptr, xg1b, nullptr, hst1, cst1, hfin, ring1,
      /*ngroup*/64, /*dir_base*/1, /*nsteps*/1, /*step_base*/0,
      /*first*/1, /*save*/0, /*lastW*/1);

  // Layer 1 forward: xg GEMM + recurrence.
  if (full) {
    xg_gemm<<<dim3(T_ * B_ / 128, 8), dim3(256), 0, stream>>>(
        out0, wih1f, bih1f, bhh1f, xga);
    recur<2, false><<<dim3(256), dim3(512), 0, stream>>>(
        whh1f, whh1b, nullptr, nullptr, nullptr, nullptr, nullptr, nullptr,
        nullptr, xga, nullptr, hst1, cst1, hfin, ring1,
        /*ngroup*/64, /*dir_base*/0, /*nsteps*/T_, /*step_base*/0,
        /*first*/1, /*save*/0, /*lastW*/1);
  } else {
    const int nch = T_ / CH;
    for (int c = 0; c < nch; ++c) {
      xg_gemm<<<dim3(CH * B_ / 128, 8), dim3(256), 0, stream>>>(
          out0 + (size_t)c * CH * B_ * 512, wih1f, bih1f, bhh1f, xga);
      recur<2, false><<<dim3(256), dim3(512), 0, stream>>>(
          whh1f, whh1b, nullptr, nullptr, nullptr, nullptr, nullptr, nullptr,
          nullptr, xga, nullptr, hst1, cst1, hfin, ring1,
          /*ngroup*/64, /*dir_base*/0, /*nsteps*/CH, /*step_base*/c * CH,
          /*first*/c == 0 ? 1 : 0, /*save*/1, /*lastW*/c == nch - 1 ? 1 : 0);
    }
  }

  fc_kernel<<<dim3(1), dim3(512), 0, stream>>>(hfin, fcw, fcb, (float*)d_out);
}

// Round 18
// 2257.658 us; speedup vs baseline: 1.2194x; 1.0271x over previous
//
#include <hip/hip_runtime.h>

// 2-layer biLSTM, B=128 T=256 IN=64 H=256, + fc to [128,1].
// R18 = R17 (verified 2.319ms) + busy-spin poll retry (adaptive backoff) +
// CH=128 chunk candidate. 512-thread recurrence WGs, 8-way k-split (2
// waves/SIMD latency hiding), W_hh gates i,f in 64 pinned VGPRs, gates g,o
// in 144KB LDS. Cross-WG h: tagged 8B pairs, RELAXED agent atomics at MALL
// (the one proven transport; L2 fast paths failed twice - stale clean lines).
// 4-WG groups are storage-minimal (W_hh/dir = 1MB > per-CU reg+LDS).

typedef unsigned long long ull;

constexpr int B_ = 128, T_ = 256, IN_ = 64, H_ = 256;
constexpr int JW = 64;                    // hidden dims per WG (4-way j split)

#define KEEP_REG(x) asm volatile("" : "+v"(x))

__device__ __forceinline__ float sigmoid_(float x) { return 1.f / (1.f + __expf(-x)); }
__device__ __forceinline__ float tanh_(float x)    { return 1.f - 2.f / (1.f + __expf(2.f * x)); }
// hbuf row: 8 chunks of 32 padded to 36 (ks-stride = +4 banks -> spread)
__device__ __forceinline__ int hidx(int k) { return (k >> 5) * 36 + (k & 31); }
// LDS weight layout: ((gp*64+jl)*8+ks)*36 + kp
__device__ __forceinline__ int widx(int gp, int jl, int ks, int kp) {
  return ((gp * 64 + jl) * 8 + ks) * 36 + kp;
}

// BB: batch rows per group. L0M: layer-0 mode (inline x via streamed W_ih).
template<int BB, bool L0M>
__global__ __launch_bounds__(512, 1)
void recur(const float* __restrict__ whh_f, const float* __restrict__ whh_b,
           const float* __restrict__ wih_f, const float* __restrict__ wih_b,
           const float* __restrict__ bih_f, const float* __restrict__ bhh_f,
           const float* __restrict__ bih_b, const float* __restrict__ bhh_b,
           const float* __restrict__ x,     // L0: [B][T][64]
           const float* __restrict__ xg,    // L1: [ns][B][1024], biases folded
           float* __restrict__ out0,        // L0: [T][B][512]
           float* __restrict__ hstate, float* __restrict__ cstate,  // [B][256]
           float* __restrict__ hfinal,      // [B][512] (L1)
           ull* __restrict__ ring,          // [gidx][2 slots][BB*256] pairs
           int ngroup, int dir_base, int nsteps, int step_base,
           int first, int save, int lastW)
{
  const int bid = blockIdx.x;
  const int kw  = bid & 3;
  const int gr  = (bid >> 2) % ngroup;
  const int dl  = (bid >> 2) / ngroup;
  const int d   = dir_base + dl;
  const int tid = threadIdx.x;              // 0..511
  const int jl  = tid >> 3;                 // 0..63
  const int ks  = tid & 7;                  // k-slice lane (32 k each)
  const int j   = kw * JW + jl;             // global hidden index
  const int bbase = gr * BB;
  const int gidx  = dl * ngroup + gr;

  const float* whh  = d ? whh_b : whh_f;
  const float* wihp = d ? wih_b : wih_f;

  // ---- VGPR gates i(0), f(1): 64 pinned floats ----
  float wr[2][32];
  #pragma unroll
  for (int g = 0; g < 2; ++g) {
    const float* wrow = whh + (long)(g * H_ + j) * H_ + ks * 32;
    #pragma unroll
    for (int q = 0; q < 8; ++q) {
      const float4 w4 = *(const float4*)(wrow + q * 4);
      wr[g][q*4+0] = w4.x; wr[g][q*4+1] = w4.y;
      wr[g][q*4+2] = w4.z; wr[g][q*4+3] = w4.w;
    }
  }
  #pragma unroll
  for (int g = 0; g < 2; ++g)
    #pragma unroll
    for (int q = 0; q < 32; ++q) KEEP_REG(wr[g][q]);

  // ---- LDS gates g(2), o(3): staged once ----
  __shared__ alignas(16) float wlds[2 * 64 * 8 * 36];   // 147456 B
  __shared__ alignas(16) float hbuf[2][BB][288];        // 8x36 padded chunks
  __shared__ alignas(16) float xt[2][4][64];            // L0 x tiles
  #pragma unroll
  for (int gp = 0; gp < 2; ++gp) {
    const float* wrow = whh + (long)((gp + 2) * H_ + j) * H_ + ks * 32;
    float* dst = &wlds[widx(gp, jl, ks, 0)];
    #pragma unroll
    for (int q = 0; q < 8; ++q)
      *(float4*)(dst + q * 4) = *(const float4*)(wrow + q * 4);
  }

  float br[4];
  if constexpr (L0M) {
    const float* bih = d ? bih_b : bih_f;
    const float* bhh = d ? bhh_b : bhh_f;
    #pragma unroll
    for (int g = 0; g < 4; ++g) br[g] = bih[g * H_ + j] + bhh[g * H_ + j];
  }

  // h(-1) / chunk restore
  for (int idx = tid; idx < BB * H_; idx += 512) {
    const int b = idx >> 8, k = idx & 255;
    hbuf[0][b][hidx(k)] = first ? 0.f : hstate[(long)(bbase + b) * H_ + k];
  }
  float cs[BB];
  #pragma unroll
  for (int b = 0; b < BB; ++b)
    cs[b] = first ? 0.f : cstate[(long)(bbase + b) * H_ + j];

  if constexpr (L0M) {
    if (tid < BB * 64) {
      const int b = tid >> 6, kx = tid & 63;
      const int t0 = d ? T_ - 1 : 0;
      xt[0][b][kx] = x[((long)(bbase + b) * T_ + t0) * IN_ + kx];
    }
  }
  float xr[BB][4], xn[BB][4];
  if constexpr (!L0M) {
    #pragma unroll
    for (int b = 0; b < BB; ++b)
      #pragma unroll
      for (int g = 0; g < 4; ++g)
        xr[b][g] = xg[(long)(bbase + b) * 1024 + g * H_ + j];
  }
  __syncthreads();

  const long ringstride = (long)2 * BB * H_;
  constexpr int NP = 3 * JW * BB;
  constexpr int NL = (NP + 511) / 512;

  for (int s = 0; s < nsteps; ++s) {
    const int p = s & 1, wp = p ^ 1;
    const int gstep = step_base + s;

    // A2) x / xg prefetch for next step (issued before polls, used late)
    float xpre = 0.f;
    if constexpr (L0M) {
      if (s + 1 < nsteps && tid < BB * 64) {
        const int b = tid >> 6, kx = tid & 63;
        const int ttn = d ? (T_ - 2 - s) : (s + 1);
        xpre = x[((long)(bbase + b) * T_ + ttn) * IN_ + kx];
      }
    } else {
      const int sn = (s + 1 < nsteps) ? s + 1 : s;
      #pragma unroll
      for (int b = 0; b < BB; ++b)
        #pragma unroll
        for (int g = 0; g < 4; ++g)
          xn[b][g] = xg[((long)sn * B_ + bbase + b) * 1024 + g * H_ + j];
    }

    // A3) issue poll loads early: their MALL RTT overlaps the x-MAC below.
    ull vv[NL];
    if (s > 0) {
      const long roff = gidx * ringstride + (long)((gstep - 1) & 1) * (BB * H_);
      #pragma unroll
      for (int q = 0; q < NL; ++q) {
        const int pidx = tid + q * 512;
        if (pidx < NP) {
          const int psl = pidx / (JW * BB), rem = pidx % (JW * BB);
          const int kwp = psl + (psl >= kw ? 1 : 0);
          vv[q] = __hip_atomic_load(ring + roff + (rem >> 6) * H_
                                        + kwp * JW + (rem & 63),
                                    __ATOMIC_RELAXED, __HIP_MEMORY_SCOPE_AGENT);
        }
      }
    }

    float acc[BB][4];
    #pragma unroll
    for (int b = 0; b < BB; ++b)
      #pragma unroll
      for (int g = 0; g < 4; ++g) acc[b][g] = 0.f;

    // B) L0: x-MAC (thread owns x cols [ks*8, ks*8+8); weights L2-streamed)
    if constexpr (L0M) {
      #pragma unroll
      for (int g = 0; g < 4; ++g) {
        const float* wa = wihp + (long)(g * H_ + j) * IN_ + ks * 8;
        const float4 w0 = *(const float4*)(wa);
        const float4 w1 = *(const float4*)(wa + 4);
        #pragma unroll
        for (int b = 0; b < BB; ++b) {
          const float4 x0 = *(const float4*)&xt[p][b][ks * 8];
          const float4 x1 = *(const float4*)&xt[p][b][ks * 8 + 4];
          acc[b][g] = fmaf(x0.x, w0.x, acc[b][g]);
          acc[b][g] = fmaf(x0.y, w0.y, acc[b][g]);
          acc[b][g] = fmaf(x0.z, w0.z, acc[b][g]);
          acc[b][g] = fmaf(x0.w, w0.w, acc[b][g]);
          acc[b][g] = fmaf(x1.x, w1.x, acc[b][g]);
          acc[b][g] = fmaf(x1.y, w1.y, acc[b][g]);
          acc[b][g] = fmaf(x1.z, w1.z, acc[b][g]);
          acc[b][g] = fmaf(x1.w, w1.w, acc[b][g]);
        }
      }
      // write next step's x tile BEFORE the barrier (race-fix ordering)
      if (s + 1 < nsteps && tid < BB * 64) {
        const int b = tid >> 6, kx = tid & 63;
        xt[wp][b][kx] = xpre;
      }
    }

    // C) spin-check polls; busy retry (stale entries only), backoff valve
    if (s > 0) {
      const unsigned want = (unsigned)gstep;
      const long roff = gidx * ringstride + (long)((gstep - 1) & 1) * (BB * H_);
      long gd = 0;
      for (;;) {
        bool ok = true;
        #pragma unroll
        for (int q = 0; q < NL; ++q)
          if (tid + q * 512 < NP && (unsigned)(vv[q] >> 32) != want) ok = false;
        if (ok) break;
        if (++gd > (1L << 20)) break;   // bail instead of hanging
        if (gd > 4096) __builtin_amdgcn_s_sleep(1);   // backoff valve only
        #pragma unroll
        for (int q = 0; q < NL; ++q) {
          const int pidx = tid + q * 512;
          if (pidx < NP && (unsigned)(vv[q] >> 32) != want) {
            const int psl = pidx / (JW * BB), rem = pidx % (JW * BB);
            const int kwp = psl + (psl >= kw ? 1 : 0);
            vv[q] = __hip_atomic_load(ring + roff + (rem >> 6) * H_
                                          + kwp * JW + (rem & 63),
                                      __ATOMIC_RELAXED, __HIP_MEMORY_SCOPE_AGENT);
          }
        }
      }
      #pragma unroll
      for (int q = 0; q < NL; ++q) {
        const int pidx = tid + q * 512;
        if (pidx < NP) {
          const int psl = pidx / (JW * BB), rem = pidx % (JW * BB);
          const int kwp = psl + (psl >= kw ? 1 : 0);
          hbuf[p][rem >> 6][hidx(kwp * JW + (rem & 63))] =
              __uint_as_float((unsigned)vv[q]);
        }
      }
    }
    __syncthreads();   // hbuf[p] complete; orders xt write vs next-iter read

    // D) hh MAC over own 32-k slice: reg gates i,f + LDS gates g,o
    #pragma unroll
    for (int q = 0; q < 8; ++q) {
      const float4 wg = *(const float4*)&wlds[widx(0, jl, ks, q * 4)];
      const float4 wo = *(const float4*)&wlds[widx(1, jl, ks, q * 4)];
      #pragma unroll
      for (int b = 0; b < BB; ++b) {
        const float4 hv = *(const float4*)&hbuf[p][b][ks * 36 + q * 4];
        acc[b][0] = fmaf(hv.x, wr[0][q*4+0], acc[b][0]);
        acc[b][0] = fmaf(hv.y, wr[0][q*4+1], acc[b][0]);
        acc[b][0] = fmaf(hv.z, wr[0][q*4+2], acc[b][0]);
        acc[b][0] = fmaf(hv.w, wr[0][q*4+3], acc[b][0]);
        acc[b][1] = fmaf(hv.x, wr[1][q*4+0], acc[b][1]);
        acc[b][1] = fmaf(hv.y, wr[1][q*4+1], acc[b][1]);
        acc[b][1] = fmaf(hv.z, wr[1][q*4+2], acc[b][1]);
        acc[b][1] = fmaf(hv.w, wr[1][q*4+3], acc[b][1]);
        acc[b][2] = fmaf(hv.x, wg.x, acc[b][2]);
        acc[b][2] = fmaf(hv.y, wg.y, acc[b][2]);
        acc[b][2] = fmaf(hv.z, wg.z, acc[b][2]);
        acc[b][2] = fmaf(hv.w, wg.w, acc[b][2]);
        acc[b][3] = fmaf(hv.x, wo.x, acc[b][3]);
        acc[b][3] = fmaf(hv.y, wo.y, acc[b][3]);
        acc[b][3] = fmaf(hv.z, wo.z, acc[b][3]);
        acc[b][3] = fmaf(hv.w, wo.w, acc[b][3]);
      }
    }

    // E) 8-lane allreduce + activations (replicated across the octet)
    float hv_[BB];
    #pragma unroll
    for (int b = 0; b < BB; ++b) {
      #pragma unroll
      for (int g = 0; g < 4; ++g) {
        float a = acc[b][g];
        a += __shfl_xor(a, 1, 64);
        a += __shfl_xor(a, 2, 64);
        a += __shfl_xor(a, 4, 64);
        if constexpr (L0M) acc[b][g] = a + br[g];
        else               acc[b][g] = a + xr[b][g];
      }
      const float ig = sigmoid_(acc[b][0]);
      const float fg = sigmoid_(acc[b][1]);
      const float gg = tanh_(acc[b][2]);
      const float og = sigmoid_(acc[b][3]);
      cs[b] = fg * cs[b] + ig * gg;
      hv_[b] = og * tanh_(cs[b]);
    }

    // F) publish + stores (lane ks handles batch row b=ks)
    if (ks < BB) {
      float hmine = hv_[0], cmine = cs[0];
      #pragma unroll
      for (int b = 1; b < BB; ++b)
        if (ks == b) { hmine = hv_[b]; cmine = cs[b]; }

      if (s < nsteps - 1) {
        const ull pv = ((ull)(unsigned)(gstep + 1) << 32)
                     | (unsigned)__float_as_uint(hmine);
        __hip_atomic_store(ring + gidx * ringstride
                               + (long)(gstep & 1) * (BB * H_) + ks * H_ + j,
                           pv, __ATOMIC_RELAXED, __HIP_MEMORY_SCOPE_AGENT);
      }
      hbuf[wp][ks][hidx(j)] = hmine;

      if constexpr (L0M) {
        const int tt = d ? (T_ - 1 - gstep) : gstep;
        out0[((long)tt * B_ + bbase + ks) * 512 + d * H_ + j] = hmine;
      } else {
        if (s == nsteps - 1 && lastW)
          hfinal[(long)(bbase + ks) * 512 + (d ? H_ : 0) + j] = hmine;
      }
      if (save && s == nsteps - 1) {
        hstate[(long)(bbase + ks) * H_ + j] = hmine;
        cstate[(long)(bbase + ks) * H_ + j] = cmine;
      }
    }

    // deferred reg update of prefetched xg (registers: no hazard)
    if constexpr (!L0M) {
      #pragma unroll
      for (int b = 0; b < BB; ++b)
        #pragma unroll
        for (int g = 0; g < 4; ++g) xr[b][g] = xn[b][g];
    }
  }
}

// C[M][1024] = A[M][512] @ W[1024][512]^T + b1 + b2.  M = gridDim.x*128.
__global__ __launch_bounds__(256, 2)
void xg_gemm(const float* __restrict__ A, const float* __restrict__ W,
             const float* __restrict__ b1, const float* __restrict__ b2,
             float* __restrict__ C)
{
  __shared__ float As[16][128];
  __shared__ float Bs[16][132];
  const int tid = threadIdx.x;
  const int tx = tid & 15, ty = tid >> 4;
  const long m0 = (long)blockIdx.x * 128;
  const int  n0 = blockIdx.y * 128;
  const int sr = tid >> 1;
  const int sk = (tid & 1) * 8;
  const float* Ar = A + (m0 + sr) * 512 + sk;
  const float* Wr = W + (long)(n0 + sr) * 512 + sk;
  float acc[8][8];
  #pragma unroll
  for (int i = 0; i < 8; ++i)
    #pragma unroll
    for (int jj = 0; jj < 8; ++jj) acc[i][jj] = 0.f;

  for (int k0 = 0; k0 < 512; k0 += 16) {
    const float4 a0 = *(const float4*)(Ar + k0);
    const float4 a1 = *(const float4*)(Ar + k0 + 4);
    const float4 w0 = *(const float4*)(Wr + k0);
    const float4 w1 = *(const float4*)(Wr + k0 + 4);
    __syncthreads();
    As[sk+0][sr]=a0.x; As[sk+1][sr]=a0.y; As[sk+2][sr]=a0.z; As[sk+3][sr]=a0.w;
    As[sk+4][sr]=a1.x; As[sk+5][sr]=a1.y; As[sk+6][sr]=a1.z; As[sk+7][sr]=a1.w;
    Bs[sk+0][sr]=w0.x; Bs[sk+1][sr]=w0.y; Bs[sk+2][sr]=w0.z; Bs[sk+3][sr]=w0.w;
    Bs[sk+4][sr]=w1.x; Bs[sk+5][sr]=w1.y; Bs[sk+6][sr]=w1.z; Bs[sk+7][sr]=w1.w;
    __syncthreads();
    #pragma unroll
    for (int k = 0; k < 16; ++k) {
      const float4 av0 = *(const float4*)&As[k][ty * 8];
      const float4 av1 = *(const float4*)&As[k][ty * 8 + 4];
      const float4 bv0 = *(const float4*)&Bs[k][tx * 8];
      const float4 bv1 = *(const float4*)&Bs[k][tx * 8 + 4];
      const float a_[8] = {av0.x,av0.y,av0.z,av0.w,av1.x,av1.y,av1.z,av1.w};
      const float b_[8] = {bv0.x,bv0.y,bv0.z,bv0.w,bv1.x,bv1.y,bv1.z,bv1.w};
      #pragma unroll
      for (int i = 0; i < 8; ++i)
        #pragma unroll
        for (int jj = 0; jj < 8; ++jj)
          acc[i][jj] = fmaf(a_[i], b_[jj], acc[i][jj]);
    }
  }
  float bsum[8];
  #pragma unroll
  for (int jj = 0; jj < 8; ++jj) {
    const int col = n0 + tx * 8 + jj;
    bsum[jj] = b1[col] + b2[col];
  }
  #pragma unroll
  for (int i = 0; i < 8; ++i) {
    const long crow = m0 + ty * 8 + i;
    #pragma unroll
    for (int q = 0; q < 2; ++q) {
      float4 o;
      o.x = acc[i][q*4+0] + bsum[q*4+0];
      o.y = acc[i][q*4+1] + bsum[q*4+1];
      o.z = acc[i][q*4+2] + bsum[q*4+2];
      o.w = acc[i][q*4+3] + bsum[q*4+3];
      *(float4*)&C[crow * 1024 + n0 + tx * 8 + q * 4] = o;
    }
  }
}

__global__ void fc_kernel(const float* __restrict__ hfinal,
                          const float* __restrict__ fc_w,
                          const float* __restrict__ fc_b,
                          float* __restrict__ out)
{
  const int tid = threadIdx.x;   // 512 threads: b = tid/4, quarter = tid%4
  const int b = tid >> 2, q = tid & 3;
  float s = 0.f;
  const float* hp = hfinal + b * 512 + q * 128;
  const float* wp = fc_w + q * 128;
  #pragma unroll 4
  for (int k = 0; k < 128; ++k) s += hp[k] * wp[k];
  s += __shfl_xor(s, 1, 64);
  s += __shfl_xor(s, 2, 64);
  if (q == 0) out[b] = s + fc_b[0];
}

extern "C" void kernel_launch(void* const* d_in, const int* in_sizes, int n_in,
                              void* d_out, int out_size, void* d_ws, size_t ws_size,
                              hipStream_t stream)
{
  const float* x     = (const float*)d_in[0];
  const float* wih0f = (const float*)d_in[1];
  const float* whh0f = (const float*)d_in[2];
  const float* bih0f = (const float*)d_in[3];
  const float* bhh0f = (const float*)d_in[4];
  const float* wih0b = (const float*)d_in[5];
  const float* whh0b = (const float*)d_in[6];
  const float* bih0b = (const float*)d_in[7];
  const float* bhh0b = (const float*)d_in[8];
  const float* wih1f = (const float*)d_in[9];
  const float* whh1f = (const float*)d_in[10];
  const float* bih1f = (const float*)d_in[11];
  const float* bhh1f = (const float*)d_in[12];
  const float* wih1b = (const float*)d_in[13];
  const float* whh1b = (const float*)d_in[14];
  const float* bih1b = (const float*)d_in[15];
  const float* bhh1b = (const float*)d_in[16];
  const float* fcw   = (const float*)d_in[17];
  const float* fcb   = (const float*)d_in[18];

  const size_t n_out0 = (size_t)T_ * B_ * 512;
  const size_t nring0 = 64ull * 2 * 4 * 256;   // ull: L0 (BB=4)
  const size_t nring1 = 64ull * 2 * 2 * 256;   // ull: L1 (BB=2)
  const size_t ringB  = (nring0 + nring1) * sizeof(ull);
  const size_t fixedf = n_out0 + (size_t)B_ * 1024 + 2 * (size_t)B_ * 256
                      + (size_t)B_ * 512;

  // xg area: full T-precompute if it fits, else chunked (larger first).
  int CH = 0; bool full = false;
  if (4 * (fixedf + (size_t)T_ * B_ * 1024) + ringB <= ws_size) {
    full = true; CH = T_;
  } else {
    const int cands[5] = {128, 64, 32, 16, 8};
    for (int i = 0; i < 5; ++i)
      if (4 * (fixedf + (size_t)cands[i] * B_ * 1024) + ringB <= ws_size) {
        CH = cands[i]; break;
      }
  }
  if (!CH) return;

  float* out0 = (float*)d_ws;
  float* xga  = out0 + n_out0;                      // [CH][B][1024]
  float* xg1b = xga + (size_t)CH * B_ * 1024;       // [1][B][1024]
  float* hst1 = xg1b + (size_t)B_ * 1024;
  float* cst1 = hst1 + (size_t)B_ * 256;
  float* hfin = cst1 + (size_t)B_ * 256;            // [B][512]
  ull*  ring0 = (ull*)(hfin + (size_t)B_ * 512);
  ull*  ring1 = ring0 + nring0;

  hipMemsetAsync(ring0, 0, ringB, stream);

  // Layer 0: 2 dirs x 32 groups (BB=4) x 4 member WGs = 256 WGs, 1/CU.
  recur<4, true><<<dim3(256), dim3(512), 0, stream>>>(
      whh0f, whh0b, wih0f, wih0b, bih0f, bhh0f, bih0b, bhh0b,
      x, nullptr, out0, nullptr, nullptr, nullptr, ring0,
      /*ngroup*/32, /*dir_base*/0, /*nsteps*/T_, /*step_base*/0,
      /*first*/1, /*save*/0, /*lastW*/0);

  // Layer 1 backward: only t=T-1 needed -> one xg row-block + one step.
  xg_gemm<<<dim3(1, 8), dim3(256), 0, stream>>>(
      out0 + (size_t)(T_ - 1) * B_ * 512, wih1b, bih1b, bhh1b, xg1b);
  recur<2, false><<<dim3(256), dim3(512), 0, stream>>>(
      whh1f, whh1b, nullptr, nullptr, nullptr, nullptr, nullptr, nullptr,
      nullptr, xg1b, nullptr, hst1, cst1, hfin, ring1,
      /*ngroup*/64, /*dir_base*/1, /*nsteps*/1, /*step_base*/0,
      /*first*/1, /*save*/0, /*lastW*/1);

  // Layer 1 forward: xg GEMM + recurrence.
  if (full) {
    xg_gemm<<<dim3(T_ * B_ / 128, 8), dim3(256), 0, stream>>>(
        out0, wih1f, bih1f, bhh1f, xga);
    recur<2, false><<<dim3(256), dim3(512), 0, stream>>>(
        whh1f, whh1b, nullptr, nullptr, nullptr, nullptr, nullptr, nullptr,
        nullptr, xga, nullptr, hst1, cst1, hfin, ring1,
        /*ngroup*/64, /*dir_base*/0, /*nsteps*/T_, /*step_base*/0,
        /*first*/1, /*save*/0, /*lastW*/1);
  } else {
    const int nch = T_ / CH;
    for (int c = 0; c < nch; ++c) {
      xg_gemm<<<dim3(CH * B_ / 128, 8), dim3(256), 0, stream>>>(
          out0 + (size_t)c * CH * B_ * 512, wih1f, bih1f, bhh1f, xga);
      recur<2, false><<<dim3(256), dim3(512), 0, stream>>>(
          whh1f, whh1b, nullptr, nullptr, nullptr, nullptr, nullptr, nullptr,
          nullptr, xga, nullptr, hst1, cst1, hfin, ring1,
          /*ngroup*/64, /*dir_base*/0, /*nsteps*/CH, /*step_base*/c * CH,
          /*first*/c == 0 ? 1 : 0, /*save*/1, /*lastW*/c == nch - 1 ? 1 : 0);
    }
  }

  fc_kernel<<<dim3(1), dim3(512), 0, stream>>>(hfin, fcw, fcb, (float*)d_out);
}